// Round 1
// baseline (755.233 us; speedup 1.0000x reference)
//
#include <hip/hip_runtime.h>

#define LVAL 256
#define TRI  32640        // L*(L-1)/2 upper-triangle entries
#define NEGF (-1e30f)

// offset of diagonal w (w>=1) in the diagonal-major triangle layout:
// d[w] has LVAL-w entries (i = 0 .. LVAL-1-w); d[w][i] = s[i][i+w]
__device__ __forceinline__ int offd(int w) {
    return (w - 1) * LVAL - (((w - 1) * w) >> 1);
}

// Phase 1: t[b,i,e] = max_c scores[b,i,e,c], upper triangle only,
// written in diagonal layout tdiag[b*TRI + offd(e-i) + i].
// 16 lanes per element, float4 loads -> lane-linear, fully coalesced.
__global__ void reduce_max_kernel(const float* __restrict__ scores,
                                  float* __restrict__ tdiag) {
    int gid  = blockIdx.x * blockDim.x + threadIdx.x;
    int elem = gid >> 4;                 // (b,i,e) flat index
    int sub  = gid & 15;
    if (elem >= 8 * LVAL * LVAL) return;
    int e  = elem & 255;
    int ii = (elem >> 8) & 255;
    int b  = elem >> 16;
    if (e <= ii) return;                 // lower triangle unused: skip the reads
    const float4* p = (const float4*)(scores + ((size_t)elem << 6)) + sub;
    float4 v = *p;
    float m = fmaxf(fmaxf(v.x, v.y), fmaxf(v.z, v.w));
    #pragma unroll
    for (int d = 1; d < 16; d <<= 1)
        m = fmaxf(m, __shfl_xor(m, d, 64));
    if (sub == 0) {
        int w = e - ii;
        tdiag[b * TRI + offd(w) + ii] = m;
    }
}

// Phase 2: per-batch CKY DP entirely in LDS (diagonal layout).
// s[i][i+w] = max_{j=1..w-1}( s[i][i+j] + s[i+j][i+w] ) + t[i][i+w]
// Thread<->cell mapping keeps both LDS operand reads lane-contiguous.
// Tail diagonals split the k-range across P partial threads + LDS combine.
__global__ __launch_bounds__(512, 1)
void cky_dp_kernel(const float* __restrict__ tdiag,
                   const int* __restrict__ lens,
                   float* __restrict__ out) {
    extern __shared__ float lds[];
    float* dlay = lds;            // TRI floats
    float* red  = lds + TRI;      // 512 floats partial-max scratch
    const int tid = threadIdx.x;
    const int b   = blockIdx.x;

    // init: linear coalesced copy of the whole triangle (holds t values)
    const float* tb = tdiag + b * TRI;
    for (int idx = tid; idx < TRI; idx += 512) dlay[idx] = tb[idx];
    __syncthreads();

    for (int w = 2; w < LVAL; ++w) {
        const int cells = LVAL - w;
        int logS, logP;
        if (cells >= 128)     { logS = 8; logP = 1; }   // P=2
        else if (cells >= 64) { logS = 7; logP = 2; }   // P=4
        else                  { logS = 6; logP = 3; }   // P=8
        const int S = 1 << logS;
        const int c = tid & (S - 1);
        const int p = tid >> logS;

        float best = NEGF;
        if (c < cells) {
            const int terms = w - 1;
            const int chunk = (terms + (1 << logP) - 1) >> logP;
            const int j0 = 1 + p * chunk;
            const int j1 = min(w, j0 + chunk);
            if (j0 < j1) {
                int oj  = offd(j0);          // offd(j)
                int owj = offd(w - j0);      // offd(w-j)
                for (int j = j0; j < j1; ++j) {
                    float l = dlay[oj + c];          // s[c][c+j]
                    float r = dlay[owj + c + j];     // s[c+j][c+w]
                    best = fmaxf(best, l + r);
                    oj  += LVAL - j;                 // -> offd(j+1)
                    owj -= LVAL + 1 - (w - j);       // -> offd(w-j-1)
                }
            }
        }
        red[tid] = best;
        __syncthreads();
        if (tid < cells) {
            float mm = red[tid];
            const int P = 1 << logP;
            for (int q = 1; q < P; ++q)
                mm = fmaxf(mm, red[(q << logS) + tid]);
            const int ow = offd(w);
            dlay[ow + tid] = mm + dlay[ow + tid];    // + t value already there
        }
        __syncthreads();
    }

    if (tid == 0) {
        int len = lens[b];
        len = len < 1 ? 1 : (len > LVAL - 1 ? LVAL - 1 : len);
        out[b] = dlay[offd(len)];                    // s[0][len]
    }
}

extern "C" void kernel_launch(void* const* d_in, const int* in_sizes, int n_in,
                              void* d_out, int out_size, void* d_ws, size_t ws_size,
                              hipStream_t stream) {
    const float* scores = (const float*)d_in[0];
    const int*   lens   = (const int*)d_in[1];
    float*       out    = (float*)d_out;
    float*       tdiag  = (float*)d_ws;   // 8 * TRI floats = 1.02 MB

    // Phase 1: 8*256*256 elements x 16 lanes each
    int total_threads = 8 * LVAL * LVAL * 16;
    reduce_max_kernel<<<total_threads / 256, 256, 0, stream>>>(scores, tdiag);

    // Phase 2: one workgroup per batch, 132.6 KB dynamic LDS (>64KB opt-in)
    size_t lds_bytes = (size_t)(TRI + 512) * sizeof(float);
    hipFuncSetAttribute((const void*)cky_dp_kernel,
                        hipFuncAttributeMaxDynamicSharedMemorySize,
                        (int)lds_bytes);
    cky_dp_kernel<<<8, 512, lds_bytes, stream>>>(tdiag, lens, out);
}

// Round 2
// 670.609 us; speedup vs baseline: 1.1262x; 1.1262x over previous
//
#include <hip/hip_runtime.h>

#define LVAL   256
#define ROWTOT 33536   // sum_i ceil8(255-i)  (f16 elems, padded row-major triangle)
#define COLTOT 37632   // sum_e (ceil8(e)+16) (f16 elems, padded col-major triangle)
#define NEGH2  0xFC00FC00u   // two f16 -inf
#define NEGH   ((unsigned short)0xFC00)

typedef _Float16 h2 __attribute__((ext_vector_type(2)));

__device__ __forceinline__ h2 u2h(unsigned int u) { return __builtin_bit_cast(h2, u); }
__device__ __forceinline__ unsigned int h2u(h2 h) { return __builtin_bit_cast(unsigned int, h); }
__device__ __forceinline__ unsigned short f2h(float f) { _Float16 h = (_Float16)f; return __builtin_bit_cast(unsigned short, h); }
__device__ __forceinline__ float h2f(unsigned short u) { return (float)__builtin_bit_cast(_Float16, u); }

__device__ __forceinline__ int ceil8(int n) { return (n + 7) & ~7; }
// G8(n) = sum_{v=1..n} ceil8(v)
__device__ __forceinline__ int G8(int n) { int q = n >> 3, r = n & 7; return 32 * q * (q + 1) + 8 * r * (q + 1); }
__device__ __forceinline__ int rowbase(int i) { return ROWTOT - G8(255 - i); }  // elems; row i holds s[i][k] at +(k-i-1)
__device__ __forceinline__ int colbase(int e) { return G8(e - 1) + 16 * e; }    // elems; col e holds s[k][e] at +k

// Phase 1: t[b,i,e] = max_c scores[b,i,e,c] -> f16, row-major padded triangle in d_ws.
// Upper triangle only; pads get -inf. Contiguous 2B writes (no sector amplification).
__global__ void phase1_rowmax(const float* __restrict__ scores,
                              unsigned short* __restrict__ rowG) {
    const int tid  = threadIdx.x;
    const int sub  = tid & 15;
    const int slot = tid >> 4;
    const int i = blockIdx.y, b = blockIdx.z;
    const int m = blockIdx.x * 16 + slot;          // elem index within row i
    const int alloc = ceil8(255 - i);
    if (m >= alloc) return;
    unsigned short* dst = rowG + (size_t)b * ROWTOT + rowbase(i) + m;
    const int e = i + 1 + m;
    if (e < LVAL) {
        const float4* p = (const float4*)(scores + ((((size_t)b * LVAL + i) * LVAL + e) << 6)) + sub;
        float4 v = *p;
        float mx = fmaxf(fmaxf(v.x, v.y), fmaxf(v.z, v.w));
        #pragma unroll
        for (int d = 1; d < 16; d <<= 1) mx = fmaxf(mx, __shfl_xor(mx, d));
        if (sub == 0) *dst = f2h(mx);
    } else {
        if (sub == 0) *dst = NEGH;                 // row tail pad
    }
}

// Phase 2: per-batch CKY DP. Dual f16 copies in LDS:
//   row-major (left operands, k-contiguous) + col-major (right operands, k-contiguous).
// Both stream as ds_read_b128 (8 f16/instr). t stored in place; unwritten slots / pads
// are -inf so over-reads are absorbed (plus explicit tail mask on the last chunk).
// Single barrier per diagonal; j-range split across P consecutive lanes, combined by shuffle.
__global__ __launch_bounds__(1024, 1)
void phase2_cky(const unsigned short* __restrict__ rowG,
                const int* __restrict__ lens,
                float* __restrict__ out) {
    extern __shared__ unsigned int lds[];
    unsigned int* rowD = lds;                         // ROWTOT/2 dwords
    unsigned int* colD = lds + (ROWTOT >> 1);         // COLTOT/2 dwords (16B aligned: 67072%16==0)
    unsigned short* rowH = (unsigned short*)rowD;
    unsigned short* colH = (unsigned short*)colD;
    const int tid = threadIdx.x;
    const int b   = blockIdx.x;

    // 1) fill everything with -inf pairs (pads + not-yet-written slots)
    const int TOTD = (ROWTOT + COLTOT) >> 1;
    for (int x = tid; x < TOTD; x += 1024) lds[x] = NEGH2;
    __syncthreads();

    // 2) linear load of the row-major t triangle (includes -inf row pads)
    {
        const uint4* src = (const uint4*)(rowG + (size_t)b * ROWTOT);
        uint4* dst = (uint4*)rowD;
        for (int x = tid; x < (ROWTOT * 2 / 16); x += 1024) dst[x] = src[x];
    }
    __syncthreads();

    // 3) in-LDS transpose: build the col-major copy (valid slots only; pads stay -inf)
    for (int i = 0; i < LVAL - 1; ++i) {
        const int Li = LVAL - 1 - i;
        const int rb = rowbase(i);
        for (int m2 = tid; m2 < Li; m2 += 1024) {
            const int e = i + 1 + m2;
            colH[colbase(e) + i] = rowH[rb + m2];
        }
    }
    __syncthreads();

    // 4) DP over diagonals w = 2..255
    for (int w = 2; w < LVAL; ++w) {
        const int cells = LVAL - w;
        const int logP = (cells > 128) ? 2 : (cells > 64) ? 3 : (cells > 32) ? 4
                       : (cells > 16) ? 5 : 6;
        const int P = 1 << logP;
        const int p = tid & (P - 1);
        const int c = tid >> logP;
        const int n8 = (w - 1 + 7) >> 3;             // 8-elem chunks covering k-c-1 in [0, w-2]
        const int qc = (n8 + P - 1) >> logP;         // chunks per group
        const int m0 = p * qc;
        const int m1 = min(n8, m0 + qc);

        float pm = -1e30f;
        if (c < cells && m0 < m1) {
            const int rbE = rowbase(c);
            const int cbE = colbase(c + w);
            const uint4* Lp = (const uint4*)(rowD + (rbE >> 1));   // rbE multiple of 8 -> 16B aligned
            const uint4* C4 = (const uint4*)colD;
            h2 acc = u2h(NEGH2);
            for (int m2 = m0; m2 < m1; ++m2) {
                // left: s[c][k], k = c+1+8*m2 .. +8, aligned b128
                uint4 L = Lp[m2];
                // right: s[k][e] from col copy, elems E0..E0+7, via two aligned b128 + extract
                const int E0 = cbE + c + 1 + 8 * m2;
                const int d0 = E0 >> 1;
                const int odd = E0 & 1;
                const int sh = d0 & 3;
                uint4 A  = C4[d0 >> 2];
                uint4 Bq = C4[(d0 >> 2) + 1];
                unsigned int w0 = sh == 0 ? A.x : sh == 1 ? A.y : sh == 2 ? A.z : A.w;
                unsigned int w1 = sh == 0 ? A.y : sh == 1 ? A.z : sh == 2 ? A.w : Bq.x;
                unsigned int w2 = sh == 0 ? A.z : sh == 1 ? A.w : sh == 2 ? Bq.x : Bq.y;
                unsigned int w3 = sh == 0 ? A.w : sh == 1 ? Bq.x : sh == 2 ? Bq.y : Bq.z;
                unsigned int w4 = sh == 0 ? Bq.x : sh == 1 ? Bq.y : sh == 2 ? Bq.z : Bq.w;
                if (odd) {                            // 16-bit funnel (v_alignbit)
                    w0 = (w0 >> 16) | (w1 << 16);
                    w1 = (w1 >> 16) | (w2 << 16);
                    w2 = (w2 >> 16) | (w3 << 16);
                    w3 = (w3 >> 16) | (w4 << 16);
                }
                // packed f16 add: l + r  (-inf absorbs unwritten/future slots)
                unsigned int s0 = h2u(u2h(L.x) + u2h(w0));
                unsigned int s1 = h2u(u2h(L.y) + u2h(w1));
                unsigned int s2 = h2u(u2h(L.z) + u2h(w2));
                unsigned int s3 = h2u(u2h(L.w) + u2h(w3));
                if (m2 == n8 - 1) {                   // tail mask: kill elems >= v
                    const int v = (w - 1) - (m2 << 3);
                    unsigned int ss[4] = {s0, s1, s2, s3};
                    #pragma unroll
                    for (int qd = 0; qd < 4; ++qd) {
                        if (2 * qd >= v)          ss[qd] = NEGH2;
                        else if (2 * qd + 1 >= v) ss[qd] = (ss[qd] & 0xFFFFu) | 0xFC000000u;
                    }
                    s0 = ss[0]; s1 = ss[1]; s2 = ss[2]; s3 = ss[3];
                }
                h2 t01 = __builtin_elementwise_max(u2h(s0), u2h(s1));
                h2 t23 = __builtin_elementwise_max(u2h(s2), u2h(s3));
                acc = __builtin_elementwise_max(acc, __builtin_elementwise_max(t01, t23));
            }
            pm = fmaxf((float)acc.x, (float)acc.y);
        }
        // combine P partials (consecutive lanes, intra-wave)
        for (int d = 1; d < P; d <<= 1) pm = fmaxf(pm, __shfl_xor(pm, d));

        if (p == 0 && c < cells) {
            const int rbE = rowbase(c);
            const float tv = h2f(rowH[rbE + w - 1]);  // in-place t, not yet overwritten
            const unsigned short sv = f2h(pm + tv);
            rowH[rbE + w - 1] = sv;                   // diag-w slot, disjoint from valid reads
            colH[colbase(c + w) + c] = sv;
        }
        __syncthreads();
    }

    if (tid == 0) {
        int len = lens[b];
        len = len < 1 ? 1 : (len > LVAL - 1 ? LVAL - 1 : len);
        out[b] = h2f(rowH[rowbase(0) + len - 1]);     // s[0][len]
    }
}

extern "C" void kernel_launch(void* const* d_in, const int* in_sizes, int n_in,
                              void* d_out, int out_size, void* d_ws, size_t ws_size,
                              hipStream_t stream) {
    const float* scores = (const float*)d_in[0];
    const int*   lens   = (const int*)d_in[1];
    float*       out    = (float*)d_out;
    unsigned short* rowG = (unsigned short*)d_ws;     // 8*ROWTOT f16 = 536 KB

    // Phase 1: grid covers upper triangle only (16 elems x 16 lanes per block)
    phase1_rowmax<<<dim3(16, 256, 8), 256, 0, stream>>>(scores, rowG);

    // Phase 2: one WG per batch; 142,336 B dynamic LDS (>64KB opt-in)
    size_t lds_bytes = (size_t)(ROWTOT + COLTOT) * 2;
    hipFuncSetAttribute((const void*)phase2_cky,
                        hipFuncAttributeMaxDynamicSharedMemorySize,
                        (int)lds_bytes);
    phase2_cky<<<8, 1024, lds_bytes, stream>>>(rowG, lens, out);
}

// Round 3
// 560.637 us; speedup vs baseline: 1.3471x; 1.1962x over previous
//
#include <hip/hip_runtime.h>

#define LVAL 256
#define T    32
#define NB   8
#define NEG  (-1e30f)

__device__ __forceinline__ size_t sidx(int b, int i, int e) {
    return ((size_t)b << 16) + (i << 8) + e;
}

// Phase 1: t[b,i,e] = max_c scores[b,i,e,c] -> f32 s[b][i][e], strict upper only.
// One WG per (b,i) row; 16 lanes per cell, float4 loads, 1 KiB contiguous per wave.
__global__ __launch_bounds__(256) void phase1(const float* __restrict__ scores,
                                              float* __restrict__ s) {
    const int i = blockIdx.x, b = blockIdx.y;
    const int sub = threadIdx.x & 15, slot = threadIdx.x >> 4;
    const float* row = scores + ((((size_t)b * LVAL + i) * LVAL) << 6);
    #pragma unroll 4
    for (int m0 = 0; m0 < LVAL; m0 += 16) {
        const int e = m0 + slot;
        if (e > i) {                       // uniform within each 16-lane group
            float4 v = *((const float4*)(row + ((size_t)e << 6)) + sub);
            float mx = fmaxf(fmaxf(v.x, v.y), fmaxf(v.z, v.w));
            #pragma unroll
            for (int d = 1; d < 16; d <<= 1) mx = fmaxf(mx, __shfl_xor(mx, d));
            if (sub == 0) s[sidx(b, i, e)] = mx;
        }
    }
}

// Round 0: in-block DP on the 8 diagonal blocks (w = 2..31), 64 independent WGs.
__global__ __launch_bounds__(256) void round0(float* __restrict__ s) {
    const int bi = blockIdx.x & 7, b = blockIdx.x >> 3;
    __shared__ float cur[T][T + 1];
    const int tid = threadIdx.x;
    const int lr = tid >> 5, lc = tid & 31;
    #pragma unroll
    for (int r = 0; r < 4; ++r)
        cur[lr + 8 * r][lc] = s[sidx(b, bi * T + lr + 8 * r, bi * T + lc)];
    __syncthreads();
    const int c = tid >> 3, p = tid & 7;        // 8 lanes per cell
    for (int l = 2; l < T; ++l) {
        const int cells = T - l;
        float pm = NEG;
        if (c < cells) {
            const int e0 = c + l;
            for (int k = c + 1 + p; k < e0; k += 8)
                pm = fmaxf(pm, cur[c][k] + cur[k][e0]);
        }
        #pragma unroll
        for (int d = 1; d < 8; d <<= 1) pm = fmaxf(pm, __shfl_xor(pm, d));
        // writes hit diag l; reads at this step only touch diags < l -> one barrier
        if (c < cells && p == 0) cur[c][c + l] += pm;
        __syncthreads();
    }
    #pragma unroll
    for (int r = 0; r < 4; ++r) {
        const int row = lr + 8 * r;
        if (lc > row) s[sidx(b, bi * T + row, bi * T + lc)] = cur[row][lc];
    }
}

// Round D (1..7): one WG per (batch, bi). Max-plus GEMM over middle K blocks
// (all precomputed), then 63-step in-block pass for k in the two edge blocks.
__global__ __launch_bounds__(256) void roundD(float* __restrict__ s, int D) {
    const int nbi = NB - D;
    const int bi = blockIdx.x % nbi;
    const int b  = blockIdx.x / nbi;
    const int be = bi + D;
    __shared__ float Ae[T][T + 1], Be[T][T + 1], cur[T][T + 1], tb[T][T + 1];
    const int tid = threadIdx.x;
    const int lr = tid >> 5, lc = tid & 31;

    // GEMM part: acc[i][e] = max over K strictly between, k in K: s[i][k]+s[k][e]
    float acc[4] = {NEG, NEG, NEG, NEG};
    for (int K = bi + 1; K < be; ++K) {
        #pragma unroll
        for (int r = 0; r < 4; ++r) {
            Ae[lr + 8 * r][lc] = s[sidx(b, bi * T + lr + 8 * r, K * T + lc)];
            Be[lr + 8 * r][lc] = s[sidx(b, K * T + lr + 8 * r, be * T + lc)];
        }
        __syncthreads();
        for (int k = 0; k < T; ++k) {
            const float bv = Be[k][lc];              // lane-consecutive, conflict-free
            #pragma unroll
            for (int r = 0; r < 4; ++r)
                acc[r] = fmaxf(acc[r], Ae[lr + 8 * r][k] + bv);  // row broadcast
        }
        __syncthreads();
    }

    // Edge blocks (both diag-0, final) + target t values + acc into LDS
    #pragma unroll
    for (int r = 0; r < 4; ++r) {
        const int row = lr + 8 * r;
        Ae[row][lc] = s[sidx(b, bi * T + row, bi * T + lc)];
        Be[row][lc] = s[sidx(b, be * T + row, be * T + lc)];
        tb[row][lc] = s[sidx(b, bi * T + row, be * T + lc)];
        cur[row][lc] = acc[r];
    }
    __syncthreads();

    // In-block sequential pass: local diagonals delta = le-li = -31..31.
    // Reads only touch same-block cells with smaller delta (finalized) -> 1 barrier/step.
    const int c = tid >> 3, p = tid & 7;
    for (int l = 0; l < 2 * T - 1; ++l) {
        const int delta = l - (T - 1);
        const int ad = delta < 0 ? -delta : delta;
        const int cells = T - ad;
        float pm = NEG;
        int li = 0, le = 0;
        if (c < cells) {
            li = c + (delta < 0 ? -delta : 0);
            le = li + delta;
            for (int lk = li + 1 + p; lk < T; lk += 8)      // k in left edge block
                pm = fmaxf(pm, Ae[li][lk] + cur[lk][le]);
            for (int lk = p; lk < le; lk += 8)              // k in right edge block
                pm = fmaxf(pm, cur[li][lk] + Be[lk][le]);
        }
        #pragma unroll
        for (int d = 1; d < 8; d <<= 1) pm = fmaxf(pm, __shfl_xor(pm, d));
        if (c < cells && p == 0) {
            float v;
            if (D * T + delta == 1) v = tb[li][le];          // w==1: value stays t
            else v = fmaxf(cur[li][le], pm) + tb[li][le];
            cur[li][le] = v;
        }
        __syncthreads();
    }

    #pragma unroll
    for (int r = 0; r < 4; ++r)
        s[sidx(b, bi * T + lr + 8 * r, be * T + lc)] = cur[lr + 8 * r][lc];
}

__global__ void finalize(const float* __restrict__ s,
                         const int* __restrict__ lens,
                         float* __restrict__ out) {
    const int b = threadIdx.x;
    if (b < 8) {
        int len = lens[b];
        len = len < 1 ? 1 : (len > LVAL - 1 ? LVAL - 1 : len);
        out[b] = s[sidx(b, 0, len)];
    }
}

extern "C" void kernel_launch(void* const* d_in, const int* in_sizes, int n_in,
                              void* d_out, int out_size, void* d_ws, size_t ws_size,
                              hipStream_t stream) {
    const float* scores = (const float*)d_in[0];
    const int*   lens   = (const int*)d_in[1];
    float*       out    = (float*)d_out;
    float*       s      = (float*)d_ws;         // 8 * 256 * 256 f32 = 2 MB

    phase1<<<dim3(LVAL, 8), 256, 0, stream>>>(scores, s);
    round0<<<64, 256, 0, stream>>>(s);
    for (int D = 1; D < NB; ++D)
        roundD<<<(NB - D) * 8, 256, 0, stream>>>(s, D);
    finalize<<<1, 64, 0, stream>>>(s, lens, out);
}

// Round 4
// 424.980 us; speedup vs baseline: 1.7771x; 1.3192x over previous
//
#include <hip/hip_runtime.h>

#define LVAL 256
#define T    32
#define ST   36          // LDS row stride in floats: 144 B, 16B-aligned, +4 bank shift/row
#define NB   8
#define NEG  (-1e30f)

__device__ __forceinline__ size_t sidx(int b, int i, int e) {
    return ((size_t)b << 16) + (i << 8) + e;
}

// Phase 1: t[b,i,e] = max_c scores[b,i,e,c] -> f32 s[b][i][e], strict upper only.
__global__ __launch_bounds__(256) void phase1(const float* __restrict__ scores,
                                              float* __restrict__ s) {
    const int i = blockIdx.x, b = blockIdx.y;
    const int sub = threadIdx.x & 15, slot = threadIdx.x >> 4;
    const float* row = scores + ((((size_t)b * LVAL + i) * LVAL) << 6);
    #pragma unroll 4
    for (int m0 = 0; m0 < LVAL; m0 += 16) {
        const int e = m0 + slot;
        if (e > i) {
            float4 v = *((const float4*)(row + ((size_t)e << 6)) + sub);
            float mx = fmaxf(fmaxf(v.x, v.y), fmaxf(v.z, v.w));
            #pragma unroll
            for (int d = 1; d < 16; d <<= 1) mx = fmaxf(mx, __shfl_xor(mx, d));
            if (sub == 0) s[sidx(b, i, e)] = mx;
        }
    }
}

// Round 0: in-block DP on the 8 diagonal blocks. cur + curT kept in sync so each
// step is 2 aligned float4 LDS reads per lane, constant loop structure.
__global__ __launch_bounds__(256) void round0(float* __restrict__ s) {
    const int bi = blockIdx.x & 7, b = blockIdx.x >> 3;
    __shared__ float cur[T][ST], curT[T][ST];
    const int tid = threadIdx.x;
    const int lr = tid >> 5, lc = tid & 31;
    #pragma unroll
    for (int r = 0; r < 4; ++r) {
        const int row = lr + 8 * r;
        float v = s[sidx(b, bi * T + row, bi * T + lc)];   // garbage at lk<=li: masked later
        cur[row][lc] = v;
        curT[lc][row] = v;
    }
    __syncthreads();
    const int c = tid >> 3, p = tid & 7, k0 = 4 * p;
    for (int l = 2; l < T; ++l) {
        const int cells = T - l;
        float pm = NEG;
        const int e0 = c + l;
        if (c < cells) {
            float4 a  = *(const float4*)&cur[c][k0];       // s[c][k], k-contiguous
            float4 bb = *(const float4*)&curT[e0][k0];     // s[k][e0], k-contiguous
            float v0 = (k0 + 0 > c && k0 + 0 < e0) ? a.x + bb.x : NEG;
            float v1 = (k0 + 1 > c && k0 + 1 < e0) ? a.y + bb.y : NEG;
            float v2 = (k0 + 2 > c && k0 + 2 < e0) ? a.z + bb.z : NEG;
            float v3 = (k0 + 3 > c && k0 + 3 < e0) ? a.w + bb.w : NEG;
            pm = fmaxf(fmaxf(v0, v1), fmaxf(v2, v3));
        }
        pm = fmaxf(pm, __shfl_xor(pm, 1));
        pm = fmaxf(pm, __shfl_xor(pm, 2));
        pm = fmaxf(pm, __shfl_xor(pm, 4));
        if (c < cells && p == 0) {
            float v = cur[c][e0] + pm;                     // slot holds t
            cur[c][e0] = v;
            curT[e0][c] = v;
        }
        __syncthreads();
    }
    #pragma unroll
    for (int r = 0; r < 4; ++r) {
        const int row = lr + 8 * r;
        if (lc > row) s[sidx(b, bi * T + row, bi * T + lc)] = cur[row][lc];
    }
}

// Round D (1..7): max-plus GEMM over middle K blocks (float4 A reads), then the
// 63-step edge pass with cur/curT/BeT giving 4 aligned b128 reads per lane-step.
__global__ __launch_bounds__(256) void roundD(float* __restrict__ s, int D) {
    const int nbi = NB - D;
    const int bi = blockIdx.x % nbi;
    const int b  = blockIdx.x / nbi;
    const int be = bi + D;
    __shared__ float Ae[T][ST], BeT[T][ST], cur[T][ST], curT[T][ST], tb[T][ST];
    const int tid = threadIdx.x;
    const int lr = tid >> 5, lc = tid & 31;

    // GEMM: acc[i][e] = max over middle K blocks of s[i][k]+s[k][e]
    float acc[4] = {NEG, NEG, NEG, NEG};
    for (int K = bi + 1; K < be; ++K) {
        #pragma unroll
        for (int r = 0; r < 4; ++r) {
            Ae[lr + 8 * r][lc]  = s[sidx(b, bi * T + lr + 8 * r, K * T + lc)];
            BeT[lr + 8 * r][lc] = s[sidx(b, K * T + lr + 8 * r, be * T + lc)]; // row-major here
        }
        __syncthreads();
        #pragma unroll
        for (int k4 = 0; k4 < T; k4 += 4) {
            const float b0 = BeT[k4 + 0][lc];
            const float b1 = BeT[k4 + 1][lc];
            const float b2 = BeT[k4 + 2][lc];
            const float b3 = BeT[k4 + 3][lc];
            #pragma unroll
            for (int r = 0; r < 4; ++r) {
                float4 a = *(const float4*)&Ae[lr + 8 * r][k4];
                acc[r] = fmaxf(acc[r],
                               fmaxf(fmaxf(a.x + b0, a.y + b1), fmaxf(a.z + b2, a.w + b3)));
            }
        }
        __syncthreads();
    }

    // Final operand load: left diag block row-major, right diag block TRANSPOSED,
    // target t block, acc into cur+curT.
    #pragma unroll
    for (int r = 0; r < 4; ++r) {
        const int row = lr + 8 * r;
        Ae[row][lc]   = s[sidx(b, bi * T + row, bi * T + lc)];
        BeT[lc][row]  = s[sidx(b, be * T + row, be * T + lc)];
        tb[row][lc]   = s[sidx(b, bi * T + row, be * T + lc)];
        cur[row][lc]  = acc[r];
        curT[lc][row] = acc[r];
    }
    __syncthreads();

    const int c = tid >> 3, p = tid & 7, k0 = 4 * p;
    for (int l = 0; l < 2 * T - 1; ++l) {
        const int delta = l - (T - 1);
        const int ad = delta < 0 ? -delta : delta;
        const int cells = T - ad;
        float pm = NEG;
        int li = 0, le = 0;
        if (c < cells) {
            li = c + (delta < 0 ? ad : 0);
            le = li + delta;
            // left-block split points: k in (li, 31]
            float4 a  = *(const float4*)&Ae[li][k0];
            float4 ct = *(const float4*)&curT[le][k0];
            float v0 = (k0 + 0 > li) ? a.x + ct.x : NEG;
            float v1 = (k0 + 1 > li) ? a.y + ct.y : NEG;
            float v2 = (k0 + 2 > li) ? a.z + ct.z : NEG;
            float v3 = (k0 + 3 > li) ? a.w + ct.w : NEG;
            // right-block split points: k in [0, le)
            float4 cr = *(const float4*)&cur[li][k0];
            float4 bt = *(const float4*)&BeT[le][k0];
            float w0 = (k0 + 0 < le) ? cr.x + bt.x : NEG;
            float w1 = (k0 + 1 < le) ? cr.y + bt.y : NEG;
            float w2 = (k0 + 2 < le) ? cr.z + bt.z : NEG;
            float w3 = (k0 + 3 < le) ? cr.w + bt.w : NEG;
            pm = fmaxf(fmaxf(fmaxf(v0, v1), fmaxf(v2, v3)),
                       fmaxf(fmaxf(w0, w1), fmaxf(w2, w3)));
        }
        pm = fmaxf(pm, __shfl_xor(pm, 1));
        pm = fmaxf(pm, __shfl_xor(pm, 2));
        pm = fmaxf(pm, __shfl_xor(pm, 4));
        if (c < cells && p == 0) {
            const float tv = tb[li][le];
            float v;
            if (D == 1 && delta == -(T - 1)) v = tv;       // w == 1: value stays t
            else v = fmaxf(cur[li][le], pm) + tv;
            cur[li][le] = v;
            curT[le][li] = v;
        }
        __syncthreads();
    }

    #pragma unroll
    for (int r = 0; r < 4; ++r)
        s[sidx(b, bi * T + lr + 8 * r, be * T + lc)] = cur[lr + 8 * r][lc];
}

__global__ void finalize(const float* __restrict__ s,
                         const int* __restrict__ lens,
                         float* __restrict__ out) {
    const int b = threadIdx.x;
    if (b < 8) {
        int len = lens[b];
        len = len < 1 ? 1 : (len > LVAL - 1 ? LVAL - 1 : len);
        out[b] = s[sidx(b, 0, len)];
    }
}

extern "C" void kernel_launch(void* const* d_in, const int* in_sizes, int n_in,
                              void* d_out, int out_size, void* d_ws, size_t ws_size,
                              hipStream_t stream) {
    const float* scores = (const float*)d_in[0];
    const int*   lens   = (const int*)d_in[1];
    float*       out    = (float*)d_out;
    float*       s      = (float*)d_ws;          // 8 * 256 * 256 f32 = 2 MB

    phase1<<<dim3(LVAL, 8), 256, 0, stream>>>(scores, s);
    round0<<<64, 256, 0, stream>>>(s);
    for (int D = 1; D < NB; ++D)
        roundD<<<(NB - D) * 8, 256, 0, stream>>>(s, D);
    finalize<<<1, 64, 0, stream>>>(s, lens, out);
}